// Round 4
// baseline (248.013 us; speedup 1.0000x reference)
//
#include <hip/hip_runtime.h>

#define HD 1024
#define BB 64
#define II 512

typedef float f4 __attribute__((ext_vector_type(4)));

__device__ __forceinline__ float fast_tanh(float x) {
    float ax = __builtin_fabsf(x);
    float e  = __builtin_amdgcn_exp2f(ax * -2.8853900817779268f);  // exp(-2|x|)
    float t  = (1.0f - e) * __builtin_amdgcn_rcpf(1.0f + e);
    return x < 0.0f ? -t : t;
}

// out[b][h] = tanh( sum_k (A[b][k] (+ rew[b]*Wr[k]+br[k])) * W[h][k] + bias[h] )
// wave = one (b, 8-h octet); lane covers k = j*256 + lane*4 (f4, coalesced on A and W).
// b range = [b0, b0 + grid*8/128)
template <int K, bool RW>
__global__ __launch_bounds__(512) void k_gemm(const float* __restrict__ A,    // [64][K]
                                              const float* __restrict__ W,    // [1024][K]
                                              const float* __restrict__ bias, // [1024]
                                              float* __restrict__ out,        // [64][1024]
                                              const float* __restrict__ rew,  // [64]
                                              const float* __restrict__ Wr,   // [K]
                                              const float* __restrict__ br,   // [K]
                                              int b0)
{
    constexpr int J = K / 256;
    int tid  = threadIdx.x;
    int lane = tid & 63;
    int wave = tid >> 6;
    int wid  = blockIdx.x * 8 + wave;
    int b    = b0 + (wid >> 7);
    int h0   = (wid & 127) * 8;
    const float* Ab = A + b * K;

    f4 a[J];
#pragma unroll
    for (int j = 0; j < J; ++j) {
        a[j] = *(const f4*)(Ab + j * 256 + lane * 4);
        if (RW) {
            float rb = rew[b];
            f4 wr4 = *(const f4*)(Wr + j * 256 + lane * 4);
            f4 br4 = *(const f4*)(br + j * 256 + lane * 4);
            a[j].x += rb * wr4.x + br4.x;
            a[j].y += rb * wr4.y + br4.y;
            a[j].z += rb * wr4.z + br4.z;
            a[j].w += rb * wr4.w + br4.w;
        }
    }
    float acc[8];
#pragma unroll
    for (int hh = 0; hh < 8; ++hh) {
        const float* wrow = W + (size_t)(h0 + hh) * K;
        float s = 0.f;
#pragma unroll
        for (int j = 0; j < J; ++j) {
            f4 w4 = *(const f4*)(wrow + j * 256 + lane * 4);
            s += a[j].x * w4.x + a[j].y * w4.y + a[j].z * w4.z + a[j].w * w4.w;
        }
        acc[hh] = s;
    }
#pragma unroll
    for (int hh = 0; hh < 8; ++hh)
#pragma unroll
        for (int off = 32; off; off >>= 1)
            acc[hh] += __shfl_xor(acc[hh], off, 64);
    if (lane == 0) {
        f4 o0, o1;
        o0.x = fast_tanh(acc[0] + bias[h0 + 0]);
        o0.y = fast_tanh(acc[1] + bias[h0 + 1]);
        o0.z = fast_tanh(acc[2] + bias[h0 + 2]);
        o0.w = fast_tanh(acc[3] + bias[h0 + 3]);
        o1.x = fast_tanh(acc[4] + bias[h0 + 4]);
        o1.y = fast_tanh(acc[5] + bias[h0 + 5]);
        o1.z = fast_tanh(acc[6] + bias[h0 + 6]);
        o1.w = fast_tanh(acc[7] + bias[h0 + 7]);
        *(f4*)(out + b * HD + h0)     = o0;
        *(f4*)(out + b * HD + h0 + 4) = o1;
    }
}

// Grouped plastic: 16 b's per launch. Block = (1 b, 8 h), wave = one (b,h) row.
// grid 2048 x 512. pw loads REGULAR so the lines allocate in L3 for update_g's re-read.
__global__ __launch_bounds__(512) void k_plastic(const float* __restrict__ pw,
                                                 const float* __restrict__ alpha,
                                                 const float* __restrict__ Wfc2,
                                                 const float* __restrict__ bfc2,
                                                 const float* __restrict__ x,      // [64][1024]
                                                 float* __restrict__ pre,          // [64][1024]
                                                 float* __restrict__ hidden,       // [64][1024]
                                                 int b0)
{
    __shared__ float xs[HD];
    int tid  = threadIdx.x;
    int lane = tid & 63;
    int wave = tid >> 6;
    int bb   = blockIdx.x >> 7;          // 0..15
    int hg   = blockIdx.x & 127;         // h-octet
    int b    = b0 + bb;
    int h    = hg * 8 + wave;

    if (tid < 256) ((f4*)xs)[tid] = ((const f4*)(x + ((size_t)b << 10)))[tid];
    __syncthreads();

    const float* pr = pw + ((size_t)b << 20) + ((size_t)h << 10);
    const float* ar = alpha + ((size_t)h << 10);
    const float* wr = Wfc2 + ((size_t)h << 10);

    float accp = 0.f, acci = 0.f;
#pragma unroll
    for (int j = 0; j < 4; ++j) {
        int i = j * 256 + lane * 4;
        f4 p4 = *(const f4*)(pr + i);
        f4 a4 = *(const f4*)(ar + i);
        f4 w4 = *(const f4*)(wr + i);
        f4 x4 = *(const f4*)(xs + i);
        accp += a4.x * p4.x * x4.x + a4.y * p4.y * x4.y +
                a4.z * p4.z * x4.z + a4.w * p4.w * x4.w;
        acci += w4.x * x4.x + w4.y * x4.y + w4.z * x4.z + w4.w * x4.w;
    }
#pragma unroll
    for (int off = 32; off; off >>= 1) {
        accp += __shfl_xor(accp, off, 64);
        acci += __shfl_xor(acci, off, 64);
    }
    if (lane == 0) {
        float pv = acci + bfc2[h] + accp;
        pre[((size_t)b << 10) + h]    = pv;
        hidden[((size_t)b << 10) + h] = fast_tanh(pv);
    }
}

// per-b heads for 16 b's: nm (tanh dots of hrc), choice (sigmoid), value
__global__ __launch_bounds__(256) void k_heads(const float* __restrict__ hidden,  // [64][1024]
                                               const float* __restrict__ hrc,     // [64][1024]
                                               const float* __restrict__ Wnm, const float* __restrict__ bnm,
                                               const float* __restrict__ Wch, const float* __restrict__ bch,
                                               const float* __restrict__ Wv,  const float* __restrict__ bv,
                                               float* __restrict__ out_choice,
                                               float* __restrict__ out_nm,
                                               float* __restrict__ out_value,
                                               float* __restrict__ nm_ws,
                                               int b0) {
    int b = b0 + blockIdx.x;
    int tid = threadIdx.x;
    float a0 = 0.f, a1 = 0.f, a2 = 0.f, a3 = 0.f;
    for (int k = tid; k < HD; k += 256) {
        float hv = hidden[(b << 10) + k];
        float rv = hrc[(b << 10) + k];
        a0 += Wnm[k] * rv;
        a1 += Wnm[HD + k] * rv;
        a2 += Wch[k] * hv;
        a3 += Wv[k] * hv;
    }
    int lane = tid & 63, wave = tid >> 6;
#pragma unroll
    for (int off = 32; off; off >>= 1) {
        a0 += __shfl_xor(a0, off, 64);
        a1 += __shfl_xor(a1, off, 64);
        a2 += __shfl_xor(a2, off, 64);
        a3 += __shfl_xor(a3, off, 64);
    }
    __shared__ float red[4][4];
    if (lane == 0) { red[wave][0] = a0; red[wave][1] = a1; red[wave][2] = a2; red[wave][3] = a3; }
    __syncthreads();
    if (tid == 0) {
        float s0 = red[0][0] + red[1][0] + red[2][0] + red[3][0];
        float s1 = red[0][1] + red[1][1] + red[2][1] + red[3][1];
        float s2 = red[0][2] + red[1][2] + red[2][2] + red[3][2];
        float s3 = red[0][3] + red[1][3] + red[2][3] + red[3][3];
        float n0 = fast_tanh(s0 + bnm[0]);
        float n1 = fast_tanh(s1 + bnm[1]);
        float nv = n0 - n1;
        out_nm[b] = nv;
        nm_ws[b]  = nv;
        float z = s2 + bch[0];
        out_choice[b] = __builtin_amdgcn_rcpf(1.0f + __builtin_amdgcn_exp2f(-z * 1.4426950408889634f));
        out_value[b] = s3 + bv[0];
    }
}

// Grouped update: 16 b's (64 MB) per launch, right after that group's plastic ->
// pw re-read comes from L3. NT loads (last use) + NT stores (don't evict pw).
__global__ __launch_bounds__(256) void k_update(const float* __restrict__ pw,
                                                const float* __restrict__ pre, // [64][1024]
                                                const float* __restrict__ x,   // [64][1024]
                                                const float* __restrict__ nm,  // [64]
                                                float* __restrict__ out,
                                                int b0) {
    int t = blockIdx.x * 256 + threadIdx.x;      // 0..524287
    const int stride = 2048 * 256;               // 524288 f4 per stripe
#pragma unroll
    for (int it = 0; it < 8; ++it) {
        int f = t + it * stride;                 // f4 index within group, 0..4M-1
        int bl = f >> 18;                        // 256K f4 per b
        int b  = b0 + bl;
        size_t e = ((size_t)b << 20) + (((size_t)(f & 0x3FFFF)) << 2);
        int h = (f >> 8) & 1023;
        int i = (f & 255) << 2;
        f4 p4 = __builtin_nontemporal_load((const f4*)(pw + e));
        f4 x4 = *(const f4*)(x + (b << 10) + i);
        float ps = pre[(b << 10) + h];
        float nb = nm[b];
        f4 o4;
        o4.x = fminf(fmaxf(p4.x + nb * fast_tanh(ps * x4.x), -50.f), 50.f);
        o4.y = fminf(fmaxf(p4.y + nb * fast_tanh(ps * x4.y), -50.f), 50.f);
        o4.z = fminf(fmaxf(p4.z + nb * fast_tanh(ps * x4.z), -50.f), 50.f);
        o4.w = fminf(fmaxf(p4.w + nb * fast_tanh(ps * x4.w), -50.f), 50.f);
        __builtin_nontemporal_store(o4, (f4*)(out + e));
    }
}

extern "C" void kernel_launch(void* const* d_in, const int* in_sizes, int n_in,
                              void* d_out, int out_size, void* d_ws, size_t ws_size,
                              hipStream_t stream) {
    const float* items  = (const float*)d_in[0];
    const float* pw     = (const float*)d_in[1];
    const float* reward = (const float*)d_in[2];
    const float* We     = (const float*)d_in[3];
    const float* be     = (const float*)d_in[4];
    const float* W1     = (const float*)d_in[5];
    const float* b1     = (const float*)d_in[6];
    const float* W2     = (const float*)d_in[7];
    const float* b2     = (const float*)d_in[8];
    const float* Wfc2   = (const float*)d_in[9];
    const float* bfc2   = (const float*)d_in[10];
    const float* Whr    = (const float*)d_in[11];
    const float* bhr    = (const float*)d_in[12];
    const float* Wch    = (const float*)d_in[13];
    const float* bch    = (const float*)d_in[14];
    const float* Wr     = (const float*)d_in[15];
    const float* br     = (const float*)d_in[16];
    const float* Wnm    = (const float*)d_in[17];
    const float* bnm    = (const float*)d_in[18];
    const float* alpha  = (const float*)d_in[19];
    const float* Wv     = (const float*)d_in[20];
    const float* bv     = (const float*)d_in[21];

    float* ws   = (float*)d_ws;
    float* x0   = ws;                // 65536
    float* x1   = ws + 65536;        // 65536
    float* x2   = ws + 131072;       // 65536
    float* preb = ws + 196608;       // 65536
    float* hrc  = ws + 262144;       // 65536
    float* nm   = ws + 327680;       // 64

    float* out        = (float*)d_out;
    float* out_choice = out;                        // 64
    float* out_nm     = out + 64;                   // 64
    float* out_value  = out + 128;                  // 64
    float* out_newpw  = out + 192;                  // 67,108,864
    float* out_hidden = out + 192 + BB * HD * HD;   // 65,536

    k_gemm<II, false><<<1024, 512, 0, stream>>>(items, We, be, x0, nullptr, nullptr, nullptr, 0);
    k_gemm<HD, false><<<1024, 512, 0, stream>>>(x0, W1, b1, x1, nullptr, nullptr, nullptr, 0);
    k_gemm<HD, false><<<1024, 512, 0, stream>>>(x1, W2, b2, x2, nullptr, nullptr, nullptr, 0);

    for (int g = 0; g < 4; ++g) {
        int b0 = g * 16;
        k_plastic<<<2048, 512, 0, stream>>>(pw, alpha, Wfc2, bfc2, x2, preb, out_hidden, b0);
        k_gemm<HD, true><<<256, 512, 0, stream>>>(out_hidden, Whr, bhr, hrc, reward, Wr, br, b0);
        k_heads<<<16, 256, 0, stream>>>(out_hidden, hrc, Wnm, bnm, Wch, bch, Wv, bv,
                                        out_choice, out_nm, out_value, nm, b0);
        k_update<<<2048, 256, 0, stream>>>(pw, preb, x2, nm, out_newpw, b0);
    }
}

// Round 5
// 179.062 us; speedup vs baseline: 1.3851x; 1.3851x over previous
//
#include <hip/hip_runtime.h>

#define HD 1024
#define BB 64
#define II 512

typedef float f4 __attribute__((ext_vector_type(4)));

__device__ __forceinline__ float fast_tanh(float x) {
    float ax = __builtin_fabsf(x);
    float e  = __builtin_amdgcn_exp2f(ax * -2.8853900817779268f);  // exp(-2|x|)
    float t  = (1.0f - e) * __builtin_amdgcn_rcpf(1.0f + e);
    return x < 0.0f ? -t : t;
}

// out[b][h] = tanh( sum_k (A[b][k] (+ rew[b]*Wr[k]+br[k])) * W[h][k] + bias[h] )
// Block = 1024 thr = 16 waves = 16 b's sharing one h-octet whose 8 W rows
// (contiguous 8K floats) are staged in LDS once -> W L2 traffic /16.
// grid 512 = 128 octets x 4 b-groups.
template <int K, bool RW>
__global__ __launch_bounds__(1024) void k_gemm(const float* __restrict__ A,    // [64][K]
                                               const float* __restrict__ W,    // [1024][K]
                                               const float* __restrict__ bias, // [1024]
                                               float* __restrict__ out,        // [64][1024]
                                               const float* __restrict__ rew,  // [64]
                                               const float* __restrict__ Wr,   // [K]
                                               const float* __restrict__ br)   // [K]
{
    constexpr int J   = K / 256;
    constexpr int LSZ = RW ? 10 * K : 8 * K;
    __shared__ float wlds[LSZ];

    int tid  = threadIdx.x;
    int oct  = blockIdx.x & 127;
    int bg   = blockIdx.x >> 7;          // 0..3
    int h0   = oct * 8;

    {   // stage 8 contiguous W rows (8*K floats) + optionally Wr, br
        const f4* src = (const f4*)(W + (size_t)h0 * K);
        f4* dst = (f4*)wlds;
#pragma unroll
        for (int v = tid; v < 2 * K; v += 1024) dst[v] = src[v];
        if (RW) {
            const f4* wrs = (const f4*)Wr;
            const f4* brs = (const f4*)br;
            f4* d2 = (f4*)(wlds + 8 * K);
            for (int v = tid; v < K / 4; v += 1024) d2[v] = wrs[v];
            f4* d3 = (f4*)(wlds + 9 * K);
            for (int v = tid; v < K / 4; v += 1024) d3[v] = brs[v];
        }
    }
    __syncthreads();

    int lane = tid & 63;
    int wave = tid >> 6;
    int b    = bg * 16 + wave;

    f4 a[J];
    float rb = RW ? rew[b] : 0.0f;
#pragma unroll
    for (int j = 0; j < J; ++j) {
        a[j] = *(const f4*)(A + (size_t)b * K + j * 256 + lane * 4);
        if (RW) {
            f4 wr4 = *(const f4*)(wlds + 8 * K + j * 256 + lane * 4);
            f4 br4 = *(const f4*)(wlds + 9 * K + j * 256 + lane * 4);
            a[j].x += rb * wr4.x + br4.x;
            a[j].y += rb * wr4.y + br4.y;
            a[j].z += rb * wr4.z + br4.z;
            a[j].w += rb * wr4.w + br4.w;
        }
    }
    float acc[8];
#pragma unroll
    for (int hh = 0; hh < 8; ++hh) {
        const float* wrow = wlds + hh * K;
        float s = 0.f;
#pragma unroll
        for (int j = 0; j < J; ++j) {
            f4 w4 = *(const f4*)(wrow + j * 256 + lane * 4);
            s += a[j].x * w4.x + a[j].y * w4.y + a[j].z * w4.z + a[j].w * w4.w;
        }
        acc[hh] = s;
    }
#pragma unroll
    for (int hh = 0; hh < 8; ++hh)
#pragma unroll
        for (int off = 32; off; off >>= 1)
            acc[hh] += __shfl_xor(acc[hh], off, 64);
    if (lane == 0) {
        f4 o0, o1;
        o0.x = fast_tanh(acc[0] + bias[h0 + 0]);
        o0.y = fast_tanh(acc[1] + bias[h0 + 1]);
        o0.z = fast_tanh(acc[2] + bias[h0 + 2]);
        o0.w = fast_tanh(acc[3] + bias[h0 + 3]);
        o1.x = fast_tanh(acc[4] + bias[h0 + 4]);
        o1.y = fast_tanh(acc[5] + bias[h0 + 5]);
        o1.z = fast_tanh(acc[6] + bias[h0 + 6]);
        o1.w = fast_tanh(acc[7] + bias[h0 + 7]);
        *(f4*)(out + (size_t)b * HD + h0)     = o0;
        *(f4*)(out + (size_t)b * HD + h0 + 4) = o1;
    }
}

// Block: 8 waves, covers 8 h x 8 b. Wave owns h, holds alpha/Wfc2 rows in regs,
// loops 8 b's; x rows staged in LDS. pw loads REGULAR (allocate so update's
// reverse-order re-read hits L3).
__global__ __launch_bounds__(512) void k_plastic(const float* __restrict__ pw,
                                                 const float* __restrict__ alpha,
                                                 const float* __restrict__ Wfc2,
                                                 const float* __restrict__ bfc2,
                                                 const float* __restrict__ x,      // [64][1024]
                                                 float* __restrict__ pre,          // [64][1024]
                                                 float* __restrict__ hidden)       // [64][1024]
{
    __shared__ float xs[8][HD];          // 32 KB
    int tid  = threadIdx.x;
    int lane = tid & 63;
    int wave = tid >> 6;
    int bg   = blockIdx.x >> 7;          // 0..7
    int hg   = blockIdx.x & 127;
    int b0   = bg * 8;
    int h    = hg * 8 + wave;

#pragma unroll
    for (int v = tid; v < 2048; v += 512) {
        int r = v >> 8, c = (v & 255) * 4;
        *(f4*)&xs[r][c] = *(const f4*)(x + ((b0 + r) << 10) + c);
    }
    __syncthreads();

    const float* ar = alpha + ((size_t)h << 10);
    const float* wr = Wfc2 + ((size_t)h << 10);
    f4 av[4], wv[4];
#pragma unroll
    for (int j = 0; j < 4; ++j) {
        av[j] = *(const f4*)(ar + j * 256 + lane * 4);
        wv[j] = *(const f4*)(wr + j * 256 + lane * 4);
    }
    float bfc = bfc2[h];

#pragma unroll
    for (int bb = 0; bb < 8; ++bb) {
        const float* prow = pw + ((size_t)(b0 + bb) << 20) + ((size_t)h << 10);
        float accp = 0.f, acci = 0.f;
#pragma unroll
        for (int j = 0; j < 4; ++j) {
            f4 p4 = *(const f4*)(prow + j * 256 + lane * 4);
            f4 x4 = *(const f4*)&xs[bb][j * 256 + lane * 4];
            accp += av[j].x * p4.x * x4.x + av[j].y * p4.y * x4.y +
                    av[j].z * p4.z * x4.z + av[j].w * p4.w * x4.w;
            acci += wv[j].x * x4.x + wv[j].y * x4.y + wv[j].z * x4.z + wv[j].w * x4.w;
        }
#pragma unroll
        for (int off = 32; off; off >>= 1) {
            accp += __shfl_xor(accp, off, 64);
            acci += __shfl_xor(acci, off, 64);
        }
        if (lane == 0) {
            float pv = acci + bfc + accp;
            pre[((b0 + bb) << 10) + h]    = pv;
            hidden[((b0 + bb) << 10) + h] = fast_tanh(pv);
        }
    }
}

// per-b heads: nm (tanh dots of hrc), choice (sigmoid dot of hidden), value (dot of hidden)
__global__ __launch_bounds__(256) void k_heads(const float* __restrict__ hidden,  // [64][1024]
                                               const float* __restrict__ hrc,     // [64][1024]
                                               const float* __restrict__ Wnm, const float* __restrict__ bnm,
                                               const float* __restrict__ Wch, const float* __restrict__ bch,
                                               const float* __restrict__ Wv,  const float* __restrict__ bv,
                                               float* __restrict__ out_choice,
                                               float* __restrict__ out_nm,
                                               float* __restrict__ out_value,
                                               float* __restrict__ nm_ws) {
    int b = blockIdx.x;
    int tid = threadIdx.x;
    float a0 = 0.f, a1 = 0.f, a2 = 0.f, a3 = 0.f;
    for (int k = tid; k < HD; k += 256) {
        float hv = hidden[(b << 10) + k];
        float rv = hrc[(b << 10) + k];
        a0 += Wnm[k] * rv;
        a1 += Wnm[HD + k] * rv;
        a2 += Wch[k] * hv;
        a3 += Wv[k] * hv;
    }
    int lane = tid & 63, wave = tid >> 6;
#pragma unroll
    for (int off = 32; off; off >>= 1) {
        a0 += __shfl_xor(a0, off, 64);
        a1 += __shfl_xor(a1, off, 64);
        a2 += __shfl_xor(a2, off, 64);
        a3 += __shfl_xor(a3, off, 64);
    }
    __shared__ float red[4][4];
    if (lane == 0) { red[wave][0] = a0; red[wave][1] = a1; red[wave][2] = a2; red[wave][3] = a3; }
    __syncthreads();
    if (tid == 0) {
        float s0 = red[0][0] + red[1][0] + red[2][0] + red[3][0];
        float s1 = red[0][1] + red[1][1] + red[2][1] + red[3][1];
        float s2 = red[0][2] + red[1][2] + red[2][2] + red[3][2];
        float s3 = red[0][3] + red[1][3] + red[2][3] + red[3][3];
        float n0 = fast_tanh(s0 + bnm[0]);
        float n1 = fast_tanh(s1 + bnm[1]);
        float nv = n0 - n1;
        out_nm[b] = nv;
        nm_ws[b]  = nv;
        float z = s2 + bch[0];
        out_choice[b] = __builtin_amdgcn_rcpf(1.0f + __builtin_amdgcn_exp2f(-z * 1.4426950408889634f));
        out_value[b] = s3 + bv[0];
    }
}

// new_pw[b,h,i] = clip(pw + nm[b]*tanh(pre[b,h]*x[b,i]), +-50)
// REVERSE traversal: plastic finished with high-b freshest in L3; read those first.
// pw loads REGULAR (probe: NT loads may forfeit L3 hits); stores NT (don't evict pw).
__global__ __launch_bounds__(256) void k_update(const float* __restrict__ pw,
                                                const float* __restrict__ pre, // [64][1024]
                                                const float* __restrict__ x,   // [64][1024]
                                                const float* __restrict__ nm,  // [64]
                                                float* __restrict__ out) {
    const int stride = 8192 * 256;   // 2,097,152 float4 per stripe
    int blk = 8191 - (int)blockIdx.x;
#pragma unroll
    for (int it = 7; it >= 0; --it) {
        int f = blk * 256 + threadIdx.x + it * stride;
        size_t e = (size_t)f << 2;
        int b = f >> 18;
        int h = (f >> 8) & 1023;
        int i = (f & 255) << 2;
        f4 p4 = *(const f4*)(pw + e);
        f4 x4 = *(const f4*)(x + (b << 10) + i);
        float ps = pre[(b << 10) + h];
        float nb = nm[b];
        f4 o4;
        o4.x = fminf(fmaxf(p4.x + nb * fast_tanh(ps * x4.x), -50.f), 50.f);
        o4.y = fminf(fmaxf(p4.y + nb * fast_tanh(ps * x4.y), -50.f), 50.f);
        o4.z = fminf(fmaxf(p4.z + nb * fast_tanh(ps * x4.z), -50.f), 50.f);
        o4.w = fminf(fmaxf(p4.w + nb * fast_tanh(ps * x4.w), -50.f), 50.f);
        __builtin_nontemporal_store(o4, (f4*)(out + e));
    }
}

extern "C" void kernel_launch(void* const* d_in, const int* in_sizes, int n_in,
                              void* d_out, int out_size, void* d_ws, size_t ws_size,
                              hipStream_t stream) {
    const float* items  = (const float*)d_in[0];
    const float* pw     = (const float*)d_in[1];
    const float* reward = (const float*)d_in[2];
    const float* We     = (const float*)d_in[3];
    const float* be     = (const float*)d_in[4];
    const float* W1     = (const float*)d_in[5];
    const float* b1     = (const float*)d_in[6];
    const float* W2     = (const float*)d_in[7];
    const float* b2     = (const float*)d_in[8];
    const float* Wfc2   = (const float*)d_in[9];
    const float* bfc2   = (const float*)d_in[10];
    const float* Whr    = (const float*)d_in[11];
    const float* bhr    = (const float*)d_in[12];
    const float* Wch    = (const float*)d_in[13];
    const float* bch    = (const float*)d_in[14];
    const float* Wr     = (const float*)d_in[15];
    const float* br     = (const float*)d_in[16];
    const float* Wnm    = (const float*)d_in[17];
    const float* bnm    = (const float*)d_in[18];
    const float* alpha  = (const float*)d_in[19];
    const float* Wv     = (const float*)d_in[20];
    const float* bv     = (const float*)d_in[21];

    float* ws   = (float*)d_ws;
    float* x0   = ws;                // 65536
    float* x1   = ws + 65536;        // 65536
    float* x2   = ws + 131072;       // 65536
    float* preb = ws + 196608;       // 65536
    float* hrc  = ws + 262144;       // 65536
    float* nm   = ws + 327680;       // 64

    float* out        = (float*)d_out;
    float* out_choice = out;                        // 64
    float* out_nm     = out + 64;                   // 64
    float* out_value  = out + 128;                  // 64
    float* out_newpw  = out + 192;                  // 67,108,864
    float* out_hidden = out + 192 + BB * HD * HD;   // 65,536

    k_gemm<II, false><<<512, 1024, 0, stream>>>(items, We, be, x0, nullptr, nullptr, nullptr);
    k_gemm<HD, false><<<512, 1024, 0, stream>>>(x0, W1, b1, x1, nullptr, nullptr, nullptr);
    k_gemm<HD, false><<<512, 1024, 0, stream>>>(x1, W2, b2, x2, nullptr, nullptr, nullptr);
    k_plastic<<<1024, 512, 0, stream>>>(pw, alpha, Wfc2, bfc2, x2, preb, out_hidden);
    k_gemm<HD, true><<<512, 1024, 0, stream>>>(out_hidden, Whr, bhr, hrc, reward, Wr, br);
    k_heads<<<64, 256, 0, stream>>>(out_hidden, hrc, Wnm, bnm, Wch, bch, Wv, bv,
                                    out_choice, out_nm, out_value, nm);
    k_update<<<8192, 256, 0, stream>>>(pw, preb, x2, nm, out_newpw);
}